// Round 6
// baseline (360.498 us; speedup 1.0000x reference)
//
#include <hip/hip_runtime.h>
#include <hip/hip_fp16.h>
#include <math.h>

#define N_NODES_C  500000
#define N_EDGES_C  8000000
#define N_GRAPHS_C 1000
#define NGROUPS_C  (N_EDGES_C / 4)     // 2,000,000 float4-groups

#define BSHIFT  11                     // bucket = recv >> 11
#define BWIDTH  2048
#define NBKT    245                    // ceil(500000 / 2048)
#define BCAP    34048                  // mean 32653 + ~7.7 sigma; mult of 4

#define EPB     4096                   // edges per part-block (16KB staged)
#define GPB     (EPB / 4)              // 1024 groups per part-block
#define NPB     ((NGROUPS_C + GPB - 1) / GPB)   // 1954 part-blocks

// ---- workspace layout (32-bit word offsets) ----
#define GRAPH_ACC_OFF 0                          // 11000 floats (atomic fallback)
#define PARTIALS_OFF  11008                      // 2*11000 floats
#define FW_OFF        33024                      // 207 floats fused weights
#define CURSOR_OFF    33280                      // 256 ints
#define NODE_ACC_OFF  33536                      // 500000 floats
#define PAIRS_OFF     533536                     // NBKT*BCAP uint32
#define PAIRS_WORDS   (NBKT * BCAP)
#define WS_WORDS_NEEDED (PAIRS_OFF + PAIRS_WORDS)
#define ZERO_HEAD     33024                      // graph_acc + partials

#define LOG2E_F 1.4426950408889634f

// fused-weight layout inside fw[]; (L) = pre-scaled by log2(e):
// 0:w_pn1[20](L) 20:b_pn1[10](L) 30:W_eb[50](L) 80:b_eb[5](L) 85:w1r0_e[5](L)
// 90:w2_e[5] 95:b2_e
// 96:w_pe1[5](L) 101:b_pe1[5](L) 106:pe_w2[50] 156:pe_b2[10]
// 166:W_nb[25](L) 191:b_nb[5](L) 196:w1r0_n[5](L) 201:w2_n[5] 206:b2_n

__device__ __forceinline__ float selu2(float xl) {
    const float C1 = 0.7282901039f;        // 1.0507009873554805 * ln(2)
    const float C2 = 1.7580993408473766f;  // scale * alpha
    float e = __builtin_amdgcn_exp2f(xl);
    float neg = fmaf(C2, e, -C2);
    return xl > 0.0f ? C1 * xl : neg;
}

__device__ __forceinline__ float selu_f(float x) {
    const float scale = 1.0507009873554805f;
    const float sa    = 1.0507009873554805f * 1.6732632423543772f;
    float neg = sa * (__expf(x) - 1.0f);
    return x > 0.0f ? scale * x : neg;
}

__device__ __forceinline__ void atomAddF(float* p, float v) {
    __hip_atomic_fetch_add(p, v, __ATOMIC_RELAXED, __HIP_MEMORY_SCOPE_AGENT);
}

__device__ __forceinline__ void fuse_weights(
        int t,
        const float* __restrict__ pn_w1, const float* __restrict__ pn_b1,
        const float* __restrict__ pn_w2, const float* __restrict__ pn_b2,
        const float* __restrict__ ue_w1, const float* __restrict__ ue_b1,
        const float* __restrict__ ue_w2, const float* __restrict__ ue_b2,
        const float* __restrict__ pe_w1, const float* __restrict__ pe_b1,
        const float* __restrict__ pe_w2, const float* __restrict__ pe_b2,
        const float* __restrict__ un_w1, const float* __restrict__ un_b1,
        const float* __restrict__ un_w2, const float* __restrict__ un_b2,
        float* __restrict__ fw) {
    const float L = LOG2E_F;
    if (t < 20) fw[0 + t] = pn_w1[t] * L;
    if (t < 10) fw[20 + t] = pn_b1[t] * L;
    if (t < 50) {
        int j = t / 5, k = t % 5;
        float s = 0.0f;
        for (int m = 0; m < 10; ++m) s += pn_w2[j * 10 + m] * ue_w1[(1 + m) * 5 + k];
        fw[30 + t] = s * L;
    }
    if (t < 5) {
        float s = ue_b1[t];
        for (int m = 0; m < 10; ++m) s += pn_b2[m] * ue_w1[(1 + m) * 5 + t];
        fw[80 + t] = s * L;
    }
    if (t < 5)  fw[85 + t]  = ue_w1[t] * L;
    if (t < 5)  fw[90 + t]  = ue_w2[t];
    if (t == 0) fw[95]      = ue_b2[0];
    if (t < 5)  fw[96 + t]  = pe_w1[t] * L;
    if (t < 5)  fw[101 + t] = pe_b1[t] * L;
    if (t < 50) fw[106 + t] = pe_w2[t];
    if (t < 10) fw[156 + t] = pe_b2[t];
    if (t < 25) {
        int j = t / 5, k = t % 5;
        float s = 0.0f;
        for (int m = 0; m < 10; ++m) s += pe_w2[j * 10 + m] * un_w1[(1 + m) * 5 + k];
        fw[166 + t] = s * L;
    }
    if (t < 5) {
        float s = un_b1[t];
        for (int m = 0; m < 10; ++m) s += pe_b2[m] * un_w1[(1 + m) * 5 + t];
        fw[191 + t] = s * L;
    }
    if (t < 5)  fw[196 + t] = un_w1[t] * L;
    if (t < 5)  fw[201 + t] = un_w2[t];
    if (t == 0) fw[206]     = un_b2[0];
}

// init: zero graph_acc+partials, set cursors; block 0 builds fused weights
__global__ __launch_bounds__(256) void k_init(
        float* __restrict__ ws,
        const float* pn_w1, const float* pn_b1, const float* pn_w2, const float* pn_b2,
        const float* ue_w1, const float* ue_b1, const float* ue_w2, const float* ue_b2,
        const float* pe_w1, const float* pe_b1, const float* pe_w2, const float* pe_b2,
        const float* un_w1, const float* un_b1, const float* un_w2, const float* un_b2) {
    int i = blockIdx.x * 256 + threadIdx.x;
    if (i < ZERO_HEAD) ws[i] = 0.0f;
    if (i < 256) ((int*)ws)[CURSOR_OFF + i] = i * BCAP;
    if (blockIdx.x == 0)
        fuse_weights(threadIdx.x, pn_w1, pn_b1, pn_w2, pn_b2, ue_w1, ue_b1, ue_w2, ue_b2,
                     pe_w1, pe_b1, pe_w2, pe_b2, un_w1, un_b1, un_w2, un_b2, ws + FW_OFF);
}

__global__ void k_fuse(const float* pn_w1, const float* pn_b1, const float* pn_w2, const float* pn_b2,
                       const float* ue_w1, const float* ue_b1, const float* ue_w2, const float* ue_b2,
                       const float* pe_w1, const float* pe_b1, const float* pe_w2, const float* pe_b2,
                       const float* un_w1, const float* un_b1, const float* un_w2, const float* un_b2,
                       float* fw) {
    fuse_weights(threadIdx.x, pn_w1, pn_b1, pn_w2, pn_b2, ue_w1, ue_b1, ue_w2, ue_b2,
                 pe_w1, pe_b1, pe_w2, pe_b2, un_w1, un_b1, un_w2, un_b2, fw);
}

__global__ void k_final(const float* __restrict__ graph_acc,
                        const float* __restrict__ partials,
                        const float* __restrict__ pr_w1, const float* __restrict__ pr_b1,
                        const float* __restrict__ pr_w2, const float* __restrict__ pr_b2,
                        float* __restrict__ out) {
    int g = blockIdx.x * blockDim.x + threadIdx.x;
    if (g >= N_GRAPHS_C) return;
    float gv[11];
#pragma unroll
    for (int f = 0; f < 11; ++f)
        gv[f] = graph_acc[g * 11 + f] + partials[g * 11 + f] + partials[11000 + g * 11 + f];
    float h[10];
#pragma unroll
    for (int j = 0; j < 10; ++j) {
        float z = pr_b1[j];
#pragma unroll
        for (int f = 0; f < 11; ++f) z = fmaf(gv[f], pr_w1[f * 10 + j], z);
        h[j] = selu_f(z);
    }
    float o[10];
    float mx = -1e30f;
#pragma unroll
    for (int j = 0; j < 10; ++j) {
        float z = pr_b2[j];
#pragma unroll
        for (int m = 0; m < 10; ++m) z = fmaf(h[m], pr_w2[m * 10 + j], z);
        o[j] = z;
        mx = fmaxf(mx, z);
    }
    float sum = 0.0f;
#pragma unroll
    for (int j = 0; j < 10; ++j) { o[j] = __expf(o[j] - mx); sum += o[j]; }
    float inv = 1.0f / sum;
#pragma unroll
    for (int j = 0; j < 10; ++j) out[g * 10 + j] = o[j] * inv;
}

// ---------------- main path ----------------

// partition: edge MLP + block-local counting sort, linear binary-search flush
// into dense global per-bucket regions.
__global__ __launch_bounds__(256) void k_part(
        const float* __restrict__ nodes, const float* __restrict__ edges,
        const int* __restrict__ senders, const int* __restrict__ receivers,
        const float* __restrict__ fw, int* __restrict__ cursor,
        unsigned int* __restrict__ pairs) {
    __shared__ int hist[256];       // inclusive counts after scan
    __shared__ int lstart[256];     // exclusive starts
    __shared__ int cursorS[256];    // running local cursor for the sort
    __shared__ int delta[256];      // gbase - lstart per bucket
    __shared__ unsigned int staged[EPB];

    int tid = threadIdx.x;
    int p   = blockIdx.x;
    int gstart = p * GPB;
    int gnum   = NGROUPS_C - gstart;
    if (gnum > GPB) gnum = GPB;

    hist[tid] = 0;
    __syncthreads();

    // ---- phase A: load receivers (kept in regs), histogram buckets ----
    int4 rv4[4];
#pragma unroll
    for (int r = 0; r < 4; ++r) {
        int idx = r * 256 + tid;
        if (idx < gnum) {
            rv4[r] = ((const int4*)receivers)[gstart + idx];
            atomicAdd(&hist[rv4[r].x >> BSHIFT], 1);
            atomicAdd(&hist[rv4[r].y >> BSHIFT], 1);
            atomicAdd(&hist[rv4[r].z >> BSHIFT], 1);
            atomicAdd(&hist[rv4[r].w >> BSHIFT], 1);
        }
    }
    __syncthreads();

    // ---- inclusive scan over 256 buckets (Hillis-Steele) ----
    int orig = hist[tid];
    int val  = orig;
    for (int d = 1; d < 256; d <<= 1) {
        int add = (tid >= d) ? hist[tid - d] : 0;
        __syncthreads();
        if (tid >= d) { val += add; hist[tid] = val; }
        __syncthreads();
    }
    int excl = val - orig;
    lstart[tid]  = excl;
    cursorS[tid] = excl;
    // global region reservation: one atomic per non-empty (block,bucket)
    if (tid < NBKT) {
        int gb = (orig > 0)
            ? __hip_atomic_fetch_add(&cursor[tid], orig, __ATOMIC_RELAXED,
                                     __HIP_MEMORY_SCOPE_AGENT)
            : tid * BCAP;
        delta[tid] = gb - excl;
    }
    __syncthreads();

    // ---- weights (wave-uniform -> scalar regs); layer-1 in log2 domain ----
    float w_pn1[20], b_pn1[10], W_eb[50], b_eb[5], w1r0[5], w2e[5];
#pragma unroll
    for (int j = 0; j < 20; ++j) w_pn1[j] = fw[j];
#pragma unroll
    for (int j = 0; j < 10; ++j) b_pn1[j] = fw[20 + j];
#pragma unroll
    for (int j = 0; j < 50; ++j) W_eb[j] = fw[30 + j];
#pragma unroll
    for (int j = 0; j < 5; ++j) b_eb[j] = fw[80 + j];
#pragma unroll
    for (int j = 0; j < 5; ++j) w1r0[j] = fw[85 + j];
#pragma unroll
    for (int j = 0; j < 5; ++j) w2e[j] = fw[90 + j];
    float b2e = fw[95];

    // ---- phase C: edge MLP, counting-sort packed pairs into LDS ----
#pragma unroll
    for (int r = 0; r < 4; ++r) {
        int idx = r * 256 + tid;
        if (idx >= gnum) continue;
        int g = gstart + idx;
        float4 e4 = ((const float4*)edges)[g];
        int4  s4 = ((const int4*)senders)[g];
        float ev[4] = {e4.x, e4.y, e4.z, e4.w};
        int   sv[4] = {s4.x, s4.y, s4.z, s4.w};
        int   rv[4] = {rv4[r].x, rv4[r].y, rv4[r].z, rv4[r].w};
        float nsv[4], nrv[4];
#pragma unroll
        for (int u = 0; u < 4; ++u) { nsv[u] = nodes[sv[u]]; nrv[u] = nodes[rv[u]]; }
#pragma unroll
        for (int u = 0; u < 4; ++u) {
            float nr = nrv[u], ns = nsv[u];
            float bs[5];
#pragma unroll
            for (int k = 0; k < 5; ++k) bs[k] = b_eb[k];
#pragma unroll
            for (int j = 0; j < 10; ++j) {
                float zl = fmaf(nr, w_pn1[j], fmaf(ns, w_pn1[10 + j], b_pn1[j]));
                float sz = selu2(zl);
#pragma unroll
                for (int k = 0; k < 5; ++k) bs[k] = fmaf(sz, W_eb[j * 5 + k], bs[k]);
            }
            float e = ev[u];
#pragma unroll
            for (int it = 0; it < 3; ++it) {
                float acc2 = b2e;
#pragma unroll
                for (int k = 0; k < 5; ++k) {
                    float tt = selu2(fmaf(e, w1r0[k], bs[k]));
                    acc2 = fmaf(tt, w2e[k], acc2);
                }
                e = acc2;
            }
            int bkt  = rv[u] >> BSHIFT;
            int slot = atomicAdd(&cursorS[bkt], 1);
            unsigned int pk = ((unsigned int)(rv[u] & (BWIDTH - 1)) << 16)
                            | (unsigned int)__half_as_ushort(__float2half_rn(e));
            staged[slot] = pk;
        }
    }
    __syncthreads();

    // ---- flush: linear over staged; bucket via 8-step binary search ----
    int fe = gnum * 4;                 // edges in this block
    for (int i = tid; i < fe; i += 256) {
        int pos = 0;                   // lower_bound: smallest pos, i < hist[pos]
#pragma unroll
        for (int s = 128; s > 0; s >>= 1) {
            int cand = pos + s;
            if (cand <= 255 && hist[cand - 1] <= i) pos = cand;
        }
        int d = i + delta[pos];
        if (d < PAIRS_WORDS) pairs[d] = staged[i];   // guard (never expected)
    }
}

// aggregate: one 1024-thread block per bucket; dense pair range -> node_acc
__global__ __launch_bounds__(1024) void k_agg(
        const int* __restrict__ cursor, const unsigned int* __restrict__ pairs,
        float* __restrict__ node_acc) {
    __shared__ float accf[BWIDTH];
    int tid = threadIdx.x;
    int b   = blockIdx.x;

    accf[tid] = 0.0f; accf[1024 + tid] = 0.0f;
    __syncthreads();

    int cnt = cursor[b] - b * BCAP;
    cnt = cnt < 0 ? 0 : (cnt > BCAP ? BCAP : cnt);

    const unsigned int* base = pairs + (size_t)b * BCAP;   // 16B-aligned
    const uint4* p4 = (const uint4*)base;
    int n4 = cnt >> 2;
    for (int i = tid; i < n4; i += 1024) {
        uint4 q = p4[i];
        atomicAdd(&accf[(q.x >> 16) & (BWIDTH - 1)],
                  __half2float(__ushort_as_half((unsigned short)(q.x & 0xffff))));
        atomicAdd(&accf[(q.y >> 16) & (BWIDTH - 1)],
                  __half2float(__ushort_as_half((unsigned short)(q.y & 0xffff))));
        atomicAdd(&accf[(q.z >> 16) & (BWIDTH - 1)],
                  __half2float(__ushort_as_half((unsigned short)(q.z & 0xffff))));
        atomicAdd(&accf[(q.w >> 16) & (BWIDTH - 1)],
                  __half2float(__ushort_as_half((unsigned short)(q.w & 0xffff))));
    }
    if (tid < (cnt & 3)) {
        unsigned int q = base[(n4 << 2) + tid];
        atomicAdd(&accf[(q >> 16) & (BWIDTH - 1)],
                  __half2float(__ushort_as_half((unsigned short)(q & 0xffff))));
    }
    __syncthreads();

#pragma unroll
    for (int q = 0; q < 2; ++q) {
        int i = (b << BSHIFT) + q * 1024 + tid;
        if (i < N_NODES_C) node_acc[i] = accf[q * 1024 + tid];
    }
}

// node MLP + atomic-free graph reduction (partials parity scheme)
__global__ __launch_bounds__(1024) void k_nodes2(
        const float* __restrict__ nodes, const int* __restrict__ graph_ids,
        const float* __restrict__ fw, const float* __restrict__ node_acc,
        float* __restrict__ graph_acc, float* __restrict__ partials) {
    __shared__ float garr[32 * 11];
    int tid = threadIdx.x;
    int b   = blockIdx.x;

    if (tid < 352) garr[tid] = 0.0f;
    __syncthreads();

    float w_pe1[5], b_pe1[5], pe_w2[50], pe_b2[10], W_nb[25], b_nb[5], w1r0n[5], w2n[5];
#pragma unroll
    for (int j = 0; j < 5; ++j) w_pe1[j] = fw[96 + j];
#pragma unroll
    for (int j = 0; j < 5; ++j) b_pe1[j] = fw[101 + j];
#pragma unroll
    for (int j = 0; j < 50; ++j) pe_w2[j] = fw[106 + j];
#pragma unroll
    for (int j = 0; j < 10; ++j) pe_b2[j] = fw[156 + j];
#pragma unroll
    for (int j = 0; j < 25; ++j) W_nb[j] = fw[166 + j];
#pragma unroll
    for (int j = 0; j < 5; ++j) b_nb[j] = fw[191 + j];
#pragma unroll
    for (int j = 0; j < 5; ++j) w1r0n[j] = fw[196 + j];
#pragma unroll
    for (int j = 0; j < 5; ++j) w2n[j] = fw[201 + j];
    float b2n = fw[206];

    int nodeBase = b << BSHIFT;
    int lastIdx  = nodeBase + BWIDTH;
    if (lastIdx > N_NODES_C) lastIdx = N_NODES_C;
    int gidBase = graph_ids[nodeBase];
    int gidEnd  = graph_ids[lastIdx - 1];

#pragma unroll
    for (int q = 0; q < 2; ++q) {
        int local = q * 1024 + tid;
        int i = nodeBase + local;
        bool valid = i < N_NODES_C;

        float s = valid ? node_acc[i] : 0.0f;
        float t5[5];
#pragma unroll
        for (int k = 0; k < 5; ++k) t5[k] = selu2(fmaf(s, w_pe1[k], b_pe1[k]));
        float he[10];
#pragma unroll
        for (int m = 0; m < 10; ++m) {
            float a = pe_b2[m];
#pragma unroll
            for (int k = 0; k < 5; ++k) a = fmaf(t5[k], pe_w2[k * 10 + m], a);
            he[m] = a;
        }
        float bs[5];
#pragma unroll
        for (int k = 0; k < 5; ++k) {
            float a = b_nb[k];
#pragma unroll
            for (int t = 0; t < 5; ++t) a = fmaf(t5[t], W_nb[t * 5 + k], a);
            bs[k] = a;
        }
        float n = valid ? nodes[i] : 0.0f;
#pragma unroll
        for (int it = 0; it < 3; ++it) {
            float a = b2n;
#pragma unroll
            for (int k = 0; k < 5; ++k) {
                float tt = selu2(fmaf(n, w1r0n[k], bs[k]));
                a = fmaf(tt, w2n[k], a);
            }
            n = a;
        }

        int gid = valid ? graph_ids[i] : -1;
        if (!valid) {
            n = 0.0f;
#pragma unroll
            for (int m = 0; m < 10; ++m) he[m] = 0.0f;
        }

        int gid0 = __shfl(gid, 0, 64);
        bool allsame = __all(gid == gid0) && (gid0 >= 0);
        if (allsame) {
            float v = n;
#pragma unroll
            for (int off = 32; off > 0; off >>= 1) v += __shfl_down(v, off, 64);
            float vh[10];
#pragma unroll
            for (int m = 0; m < 10; ++m) {
                float ww = he[m];
#pragma unroll
                for (int off = 32; off > 0; off >>= 1) ww += __shfl_down(ww, off, 64);
                vh[m] = ww;
            }
            if ((tid & 63) == 0) {
                int off = gid0 - gidBase;
                if (off >= 0 && off < 32) {
                    atomicAdd(&garr[off * 11 + 0], v);
#pragma unroll
                    for (int m = 0; m < 10; ++m) atomicAdd(&garr[off * 11 + 1 + m], vh[m]);
                } else {
                    atomAddF(&graph_acc[gid0 * 11 + 0], v);
#pragma unroll
                    for (int m = 0; m < 10; ++m) atomAddF(&graph_acc[gid0 * 11 + 1 + m], vh[m]);
                }
            }
        } else if (valid) {
            int off = gid - gidBase;
            if (off >= 0 && off < 32) {
                atomicAdd(&garr[off * 11 + 0], n);
#pragma unroll
                for (int m = 0; m < 10; ++m) atomicAdd(&garr[off * 11 + 1 + m], he[m]);
            } else {
                atomAddF(&graph_acc[gid * 11 + 0], n);
#pragma unroll
                for (int m = 0; m < 10; ++m) atomAddF(&graph_acc[gid * 11 + 1 + m], he[m]);
            }
        }
    }
    __syncthreads();

    // plain-store partials: graph spans <=2 consecutive blocks -> parity slot
    int ngl = gidEnd - gidBase + 1;
    if (ngl > 32) ngl = 32;            // overflow handled by global-atomic path
    int par = (b & 1) * 11000;
    for (int t = tid; t < ngl * 11; t += 1024) {
        int off = t / 11, f = t - off * 11;
        partials[par + (gidBase + off) * 11 + f] = garr[t];
    }
}

// ---------------- fallback path (ws too small) ----------------

__global__ __launch_bounds__(256) void k_zero(float* __restrict__ ws, int len4) {
    int i = blockIdx.x * 256 + threadIdx.x;
    if (i < len4) ((float4*)ws)[i] = make_float4(0.f, 0.f, 0.f, 0.f);
}

__global__ __launch_bounds__(256) void k_edges(
        const float* __restrict__ nodes, const float* __restrict__ edges,
        const int* __restrict__ senders, const int* __restrict__ receivers,
        const float* __restrict__ fw, float* __restrict__ node_acc) {
    float w_pn1[20], b_pn1[10], W_eb[50], b_eb[5], w1r0[5], w2e[5];
#pragma unroll
    for (int j = 0; j < 20; ++j) w_pn1[j] = fw[j];
#pragma unroll
    for (int j = 0; j < 10; ++j) b_pn1[j] = fw[20 + j];
#pragma unroll
    for (int j = 0; j < 50; ++j) W_eb[j] = fw[30 + j];
#pragma unroll
    for (int j = 0; j < 5; ++j) b_eb[j] = fw[80 + j];
#pragma unroll
    for (int j = 0; j < 5; ++j) w1r0[j] = fw[85 + j];
#pragma unroll
    for (int j = 0; j < 5; ++j) w2e[j] = fw[90 + j];
    float b2e = fw[95];

    int g = blockIdx.x * 256 + threadIdx.x;
    if (g >= NGROUPS_C) return;

    float4 e4 = ((const float4*)edges)[g];
    int4  s4 = ((const int4*)senders)[g];
    int4  r4 = ((const int4*)receivers)[g];
    float ev[4] = {e4.x, e4.y, e4.z, e4.w};
    int   sv[4] = {s4.x, s4.y, s4.z, s4.w};
    int   rv[4] = {r4.x, r4.y, r4.z, r4.w};
    float nsv[4], nrv[4];
#pragma unroll
    for (int u = 0; u < 4; ++u) { nsv[u] = nodes[sv[u]]; nrv[u] = nodes[rv[u]]; }
#pragma unroll
    for (int u = 0; u < 4; ++u) {
        float nr = nrv[u], ns = nsv[u];
        float bs[5];
#pragma unroll
        for (int k = 0; k < 5; ++k) bs[k] = b_eb[k];
#pragma unroll
        for (int j = 0; j < 10; ++j) {
            float zl = fmaf(nr, w_pn1[j], fmaf(ns, w_pn1[10 + j], b_pn1[j]));
            float sz = selu2(zl);
#pragma unroll
            for (int k = 0; k < 5; ++k) bs[k] = fmaf(sz, W_eb[j * 5 + k], bs[k]);
        }
        float e = ev[u];
#pragma unroll
        for (int it = 0; it < 3; ++it) {
            float acc2 = b2e;
#pragma unroll
            for (int k = 0; k < 5; ++k) {
                float tt = selu2(fmaf(e, w1r0[k], bs[k]));
                acc2 = fmaf(tt, w2e[k], acc2);
            }
            e = acc2;
        }
        atomAddF(&node_acc[rv[u]], e);
    }
}

__global__ __launch_bounds__(256) void k_nodes(
        const float* __restrict__ nodes, const int* __restrict__ graph_ids,
        const float* __restrict__ fw, const float* __restrict__ node_acc,
        float* __restrict__ graph_acc) {
    float w_pe1[5], b_pe1[5], pe_w2[50], pe_b2[10], W_nb[25], b_nb[5], w1r0n[5], w2n[5];
#pragma unroll
    for (int j = 0; j < 5; ++j) w_pe1[j] = fw[96 + j];
#pragma unroll
    for (int j = 0; j < 5; ++j) b_pe1[j] = fw[101 + j];
#pragma unroll
    for (int j = 0; j < 50; ++j) pe_w2[j] = fw[106 + j];
#pragma unroll
    for (int j = 0; j < 10; ++j) pe_b2[j] = fw[156 + j];
#pragma unroll
    for (int j = 0; j < 25; ++j) W_nb[j] = fw[166 + j];
#pragma unroll
    for (int j = 0; j < 5; ++j) b_nb[j] = fw[191 + j];
#pragma unroll
    for (int j = 0; j < 5; ++j) w1r0n[j] = fw[196 + j];
#pragma unroll
    for (int j = 0; j < 5; ++j) w2n[j] = fw[201 + j];
    float b2n = fw[206];

    int i = blockIdx.x * 256 + threadIdx.x;
    bool valid = i < N_NODES_C;
    int ii = valid ? i : (N_NODES_C - 1);

    float s = node_acc[ii];
    float t5[5];
#pragma unroll
    for (int k = 0; k < 5; ++k) t5[k] = selu2(fmaf(s, w_pe1[k], b_pe1[k]));
    float he[10];
#pragma unroll
    for (int m = 0; m < 10; ++m) {
        float a = pe_b2[m];
#pragma unroll
        for (int k = 0; k < 5; ++k) a = fmaf(t5[k], pe_w2[k * 10 + m], a);
        he[m] = a;
    }
    float bs[5];
#pragma unroll
    for (int k = 0; k < 5; ++k) {
        float a = b_nb[k];
#pragma unroll
        for (int t = 0; t < 5; ++t) a = fmaf(t5[t], W_nb[t * 5 + k], a);
        bs[k] = a;
    }
    float n = nodes[ii];
#pragma unroll
    for (int it = 0; it < 3; ++it) {
        float a = b2n;
#pragma unroll
        for (int k = 0; k < 5; ++k) {
            float tt = selu2(fmaf(n, w1r0n[k], bs[k]));
            a = fmaf(tt, w2n[k], a);
        }
        n = a;
    }

    int gid = valid ? graph_ids[ii] : -1;
    if (!valid) {
        n = 0.0f;
#pragma unroll
        for (int m = 0; m < 10; ++m) he[m] = 0.0f;
    }

    int gid0 = __shfl(gid, 0, 64);
    bool allsame = __all(gid == gid0) && (gid0 >= 0);
    if (allsame) {
        float v = n;
#pragma unroll
        for (int off = 32; off > 0; off >>= 1) v += __shfl_down(v, off, 64);
        float vh[10];
#pragma unroll
        for (int m = 0; m < 10; ++m) {
            float ww = he[m];
#pragma unroll
            for (int off = 32; off > 0; off >>= 1) ww += __shfl_down(ww, off, 64);
            vh[m] = ww;
        }
        if ((threadIdx.x & 63) == 0) {
            atomAddF(&graph_acc[gid0 * 11 + 0], v);
#pragma unroll
            for (int m = 0; m < 10; ++m) atomAddF(&graph_acc[gid0 * 11 + 1 + m], vh[m]);
        }
    } else if (valid) {
        atomAddF(&graph_acc[gid * 11 + 0], n);
#pragma unroll
        for (int m = 0; m < 10; ++m) atomAddF(&graph_acc[gid * 11 + 1 + m], he[m]);
    }
}

// ---------------- launch ----------------

extern "C" void kernel_launch(void* const* d_in, const int* in_sizes, int n_in,
                              void* d_out, int out_size, void* d_ws, size_t ws_size,
                              hipStream_t stream) {
    const float* nodes     = (const float*)d_in[0];
    const float* edges     = (const float*)d_in[1];
    const int*   senders   = (const int*)d_in[2];
    const int*   receivers = (const int*)d_in[3];
    const int*   graph_ids = (const int*)d_in[4];
    const float* pn_w1 = (const float*)d_in[6];
    const float* pn_b1 = (const float*)d_in[7];
    const float* pn_w2 = (const float*)d_in[8];
    const float* pn_b2 = (const float*)d_in[9];
    const float* ue_w1 = (const float*)d_in[10];
    const float* ue_b1 = (const float*)d_in[11];
    const float* ue_w2 = (const float*)d_in[12];
    const float* ue_b2 = (const float*)d_in[13];
    const float* pe_w1 = (const float*)d_in[14];
    const float* pe_b1 = (const float*)d_in[15];
    const float* pe_w2 = (const float*)d_in[16];
    const float* pe_b2 = (const float*)d_in[17];
    const float* un_w1 = (const float*)d_in[18];
    const float* un_b1 = (const float*)d_in[19];
    const float* un_w2 = (const float*)d_in[20];
    const float* un_b2 = (const float*)d_in[21];
    const float* pr_w1 = (const float*)d_in[22];
    const float* pr_b1 = (const float*)d_in[23];
    const float* pr_w2 = (const float*)d_in[24];
    const float* pr_b2 = (const float*)d_in[25];

    float* ws        = (float*)d_ws;
    float* graph_acc = ws + GRAPH_ACC_OFF;
    float* partials  = ws + PARTIALS_OFF;
    float* fw        = ws + FW_OFF;
    float* node_acc  = ws + NODE_ACC_OFF;
    float* outp      = (float*)d_out;

    if (ws_size >= (size_t)WS_WORDS_NEEDED * 4) {
        int* cursor          = (int*)ws + CURSOR_OFF;
        unsigned int* pairs  = (unsigned int*)ws + PAIRS_OFF;

        hipLaunchKernelGGL(k_init, dim3((ZERO_HEAD + 255) / 256), dim3(256), 0, stream, ws,
                           pn_w1, pn_b1, pn_w2, pn_b2, ue_w1, ue_b1, ue_w2, ue_b2,
                           pe_w1, pe_b1, pe_w2, pe_b2, un_w1, un_b1, un_w2, un_b2);
        hipLaunchKernelGGL(k_part, dim3(NPB), dim3(256), 0, stream,
                           nodes, edges, senders, receivers, fw, cursor, pairs);
        hipLaunchKernelGGL(k_agg, dim3(NBKT), dim3(1024), 0, stream,
                           cursor, pairs, node_acc);
        hipLaunchKernelGGL(k_nodes2, dim3(NBKT), dim3(1024), 0, stream,
                           nodes, graph_ids, fw, node_acc, graph_acc, partials);
        hipLaunchKernelGGL(k_final, dim3((N_GRAPHS_C + 255) / 256), dim3(256), 0, stream,
                           graph_acc, partials, pr_w1, pr_b1, pr_w2, pr_b2, outp);
    } else {
        int len4 = (NODE_ACC_OFF + N_NODES_C) / 4;
        hipLaunchKernelGGL(k_zero, dim3((len4 + 255) / 256), dim3(256), 0, stream, ws, len4);
        hipLaunchKernelGGL(k_fuse, dim3(1), dim3(64), 0, stream,
                           pn_w1, pn_b1, pn_w2, pn_b2, ue_w1, ue_b1, ue_w2, ue_b2,
                           pe_w1, pe_b1, pe_w2, pe_b2, un_w1, un_b1, un_w2, un_b2, fw);
        hipLaunchKernelGGL(k_edges, dim3((NGROUPS_C + 255) / 256), dim3(256), 0, stream,
                           nodes, edges, senders, receivers, fw, node_acc);
        hipLaunchKernelGGL(k_nodes, dim3((N_NODES_C + 255) / 256), dim3(256), 0, stream,
                           nodes, graph_ids, fw, node_acc, graph_acc);
        hipLaunchKernelGGL(k_final, dim3((N_GRAPHS_C + 255) / 256), dim3(256), 0, stream,
                           graph_acc, partials, pr_w1, pr_b1, pr_w2, pr_b2, outp);
    }
}

// Round 7
// 325.493 us; speedup vs baseline: 1.1075x; 1.1075x over previous
//
#include <hip/hip_runtime.h>
#include <hip/hip_fp16.h>
#include <math.h>

#define N_NODES_C  500000
#define N_EDGES_C  8000000
#define N_GRAPHS_C 1000
#define NGROUPS_C  (N_EDGES_C / 4)     // 2,000,000 float4-groups

#define BSHIFT  11                     // bucket = recv >> 11
#define BWIDTH  2048
#define NBKT    245                    // ceil(500000 / 2048)

#define EPB     7168                   // edges per part-block (28KB staged -> 30KB LDS -> 5 blk/CU)
#define GPB     (EPB / 4)              // 1792 groups = 7 * 256
#define NPB     ((NGROUPS_C + GPB - 1) / GPB)   // 1117 part-blocks
#define SROW    1120                   // starts_T row stride (ints), >= NPB

// ---- workspace layout (32-bit word offsets) ----
#define GRAPH_ACC_OFF 0                          // 11000 floats
#define PARTIALS_OFF  11008                      // 2*11000 floats
#define FW_OFF        33024                      // 207 floats fused weights
#define STARTS_OFF    33280                      // 246 * SROW ints
#define PAIRS_OFF     (STARTS_OFF + 246 * SROW)  // 308800; NPB*EPB uint32 (16B aligned)
#define WS_WORDS_NEEDED (PAIRS_OFF + NPB * EPB)
#define ZERO_HEAD     33024                      // graph_acc + partials
// ---- fallback layout ----
#define OLD_NODE_ACC_OFF 33536
#define OLD_ZERO_WORDS   (OLD_NODE_ACC_OFF + N_NODES_C)

#define LOG2E_F 1.4426950408889634f

// fused-weight layout inside fw[]; (L) = pre-scaled by log2(e):
// 0:w_pn1[20](L) 20:b_pn1[10](L) 30:W_eb[50](L) 80:b_eb[5](L) 85:w1r0_e[5](L)
// 90:w2_e[5] 95:b2_e
// 96:w_pe1[5](L) 101:b_pe1[5](L) 106:pe_w2[50] 156:pe_b2[10]
// 166:W_nb[25](L) 191:b_nb[5](L) 196:w1r0_n[5](L) 201:w2_n[5] 206:b2_n

__device__ __forceinline__ float selu2(float xl) {
    const float C1 = 0.7282901039f;        // 1.0507009873554805 * ln(2)
    const float C2 = 1.7580993408473766f;  // scale * alpha
    float e = __builtin_amdgcn_exp2f(xl);
    float neg = fmaf(C2, e, -C2);
    return xl > 0.0f ? C1 * xl : neg;
}

__device__ __forceinline__ float selu_f(float x) {
    const float scale = 1.0507009873554805f;
    const float sa    = 1.0507009873554805f * 1.6732632423543772f;
    float neg = sa * (__expf(x) - 1.0f);
    return x > 0.0f ? scale * x : neg;
}

__device__ __forceinline__ void atomAddF(float* p, float v) {
    __hip_atomic_fetch_add(p, v, __ATOMIC_RELAXED, __HIP_MEMORY_SCOPE_AGENT);
}

__device__ __forceinline__ void fuse_weights(
        int t,
        const float* __restrict__ pn_w1, const float* __restrict__ pn_b1,
        const float* __restrict__ pn_w2, const float* __restrict__ pn_b2,
        const float* __restrict__ ue_w1, const float* __restrict__ ue_b1,
        const float* __restrict__ ue_w2, const float* __restrict__ ue_b2,
        const float* __restrict__ pe_w1, const float* __restrict__ pe_b1,
        const float* __restrict__ pe_w2, const float* __restrict__ pe_b2,
        const float* __restrict__ un_w1, const float* __restrict__ un_b1,
        const float* __restrict__ un_w2, const float* __restrict__ un_b2,
        float* __restrict__ fw) {
    const float L = LOG2E_F;
    if (t < 20) fw[0 + t] = pn_w1[t] * L;
    if (t < 10) fw[20 + t] = pn_b1[t] * L;
    if (t < 50) {
        int j = t / 5, k = t % 5;
        float s = 0.0f;
        for (int m = 0; m < 10; ++m) s += pn_w2[j * 10 + m] * ue_w1[(1 + m) * 5 + k];
        fw[30 + t] = s * L;
    }
    if (t < 5) {
        float s = ue_b1[t];
        for (int m = 0; m < 10; ++m) s += pn_b2[m] * ue_w1[(1 + m) * 5 + t];
        fw[80 + t] = s * L;
    }
    if (t < 5)  fw[85 + t]  = ue_w1[t] * L;
    if (t < 5)  fw[90 + t]  = ue_w2[t];
    if (t == 0) fw[95]      = ue_b2[0];
    if (t < 5)  fw[96 + t]  = pe_w1[t] * L;
    if (t < 5)  fw[101 + t] = pe_b1[t] * L;
    if (t < 50) fw[106 + t] = pe_w2[t];
    if (t < 10) fw[156 + t] = pe_b2[t];
    if (t < 25) {
        int j = t / 5, k = t % 5;
        float s = 0.0f;
        for (int m = 0; m < 10; ++m) s += pe_w2[j * 10 + m] * un_w1[(1 + m) * 5 + k];
        fw[166 + t] = s * L;
    }
    if (t < 5) {
        float s = un_b1[t];
        for (int m = 0; m < 10; ++m) s += pe_b2[m] * un_w1[(1 + m) * 5 + t];
        fw[191 + t] = s * L;
    }
    if (t < 5)  fw[196 + t] = un_w1[t] * L;
    if (t < 5)  fw[201 + t] = un_w2[t];
    if (t == 0) fw[206]     = un_b2[0];
}

// init: zero graph_acc+partials; block 0 builds fused weights
__global__ __launch_bounds__(256) void k_init(
        float* __restrict__ ws,
        const float* pn_w1, const float* pn_b1, const float* pn_w2, const float* pn_b2,
        const float* ue_w1, const float* ue_b1, const float* ue_w2, const float* ue_b2,
        const float* pe_w1, const float* pe_b1, const float* pe_w2, const float* pe_b2,
        const float* un_w1, const float* un_b1, const float* un_w2, const float* un_b2) {
    int i = blockIdx.x * 256 + threadIdx.x;
    if (i < ZERO_HEAD) ws[i] = 0.0f;
    if (blockIdx.x == 0)
        fuse_weights(threadIdx.x, pn_w1, pn_b1, pn_w2, pn_b2, ue_w1, ue_b1, ue_w2, ue_b2,
                     pe_w1, pe_b1, pe_w2, pe_b2, un_w1, un_b1, un_w2, un_b2, ws + FW_OFF);
}

__global__ void k_fuse(const float* pn_w1, const float* pn_b1, const float* pn_w2, const float* pn_b2,
                       const float* ue_w1, const float* ue_b1, const float* ue_w2, const float* ue_b2,
                       const float* pe_w1, const float* pe_b1, const float* pe_w2, const float* pe_b2,
                       const float* un_w1, const float* un_b1, const float* un_w2, const float* un_b2,
                       float* fw) {
    fuse_weights(threadIdx.x, pn_w1, pn_b1, pn_w2, pn_b2, ue_w1, ue_b1, ue_w2, ue_b2,
                 pe_w1, pe_b1, pe_w2, pe_b2, un_w1, un_b1, un_w2, un_b2, fw);
}

__global__ void k_final(const float* __restrict__ graph_acc,
                        const float* __restrict__ partials,
                        const float* __restrict__ pr_w1, const float* __restrict__ pr_b1,
                        const float* __restrict__ pr_w2, const float* __restrict__ pr_b2,
                        float* __restrict__ out) {
    int g = blockIdx.x * blockDim.x + threadIdx.x;
    if (g >= N_GRAPHS_C) return;
    float gv[11];
#pragma unroll
    for (int f = 0; f < 11; ++f)
        gv[f] = graph_acc[g * 11 + f] + partials[g * 11 + f] + partials[11000 + g * 11 + f];
    float h[10];
#pragma unroll
    for (int j = 0; j < 10; ++j) {
        float z = pr_b1[j];
#pragma unroll
        for (int f = 0; f < 11; ++f) z = fmaf(gv[f], pr_w1[f * 10 + j], z);
        h[j] = selu_f(z);
    }
    float o[10];
    float mx = -1e30f;
#pragma unroll
    for (int j = 0; j < 10; ++j) {
        float z = pr_b2[j];
#pragma unroll
        for (int m = 0; m < 10; ++m) z = fmaf(h[m], pr_w2[m * 10 + j], z);
        o[j] = z;
        mx = fmaxf(mx, z);
    }
    float sum = 0.0f;
#pragma unroll
    for (int j = 0; j < 10; ++j) { o[j] = __expf(o[j] - mx); sum += o[j]; }
    float inv = 1.0f / sum;
#pragma unroll
    for (int j = 0; j < 10; ++j) out[g * 10 + j] = o[j] * inv;
}

// ---------------- main path ----------------

// partition: edge MLP + block-local counting sort, contiguous uint4 flush to
// a private per-block region; per-bucket starts recorded in starts_T.
__global__ __launch_bounds__(256) void k_part(
        const float* __restrict__ nodes, const float* __restrict__ edges,
        const int* __restrict__ senders, const int* __restrict__ receivers,
        const float* __restrict__ fw, int* __restrict__ starts_T,
        unsigned int* __restrict__ pairs) {
    __shared__ int hist[256];
    __shared__ int cursorS[256];
    __shared__ unsigned int staged[EPB];   // 28 KB

    int tid = threadIdx.x;
    int p   = blockIdx.x;
    int gstart = p * GPB;
    int gnum   = NGROUPS_C - gstart;
    if (gnum > GPB) gnum = GPB;

    // ---- weights first (uniform -> scalar loads overlap phase A) ----
    float w_pn1[20], b_pn1[10], W_eb[50], b_eb[5], w1r0[5], w2e[5];
#pragma unroll
    for (int j = 0; j < 20; ++j) w_pn1[j] = fw[j];
#pragma unroll
    for (int j = 0; j < 10; ++j) b_pn1[j] = fw[20 + j];
#pragma unroll
    for (int j = 0; j < 50; ++j) W_eb[j] = fw[30 + j];
#pragma unroll
    for (int j = 0; j < 5; ++j) b_eb[j] = fw[80 + j];
#pragma unroll
    for (int j = 0; j < 5; ++j) w1r0[j] = fw[85 + j];
#pragma unroll
    for (int j = 0; j < 5; ++j) w2e[j] = fw[90 + j];
    float b2e = fw[95];

    hist[tid] = 0;
    __syncthreads();

    // ---- phase A: load receivers (kept in regs), histogram buckets ----
    int4 rv4[7];
#pragma unroll
    for (int r = 0; r < 7; ++r) {
        int idx = r * 256 + tid;
        if (idx < gnum) {
            rv4[r] = ((const int4*)receivers)[gstart + idx];
            atomicAdd(&hist[rv4[r].x >> BSHIFT], 1);
            atomicAdd(&hist[rv4[r].y >> BSHIFT], 1);
            atomicAdd(&hist[rv4[r].z >> BSHIFT], 1);
            atomicAdd(&hist[rv4[r].w >> BSHIFT], 1);
        }
    }
    __syncthreads();

    // ---- inclusive scan over 256 buckets (Hillis-Steele) ----
    int orig = hist[tid];
    int val  = orig;
    for (int d = 1; d < 256; d <<= 1) {
        int add = (tid >= d) ? hist[tid - d] : 0;
        __syncthreads();
        if (tid >= d) { val += add; hist[tid] = val; }
        __syncthreads();
    }
    int excl = val - orig;
    cursorS[tid] = excl;
    // excl[245] == total edges of this block (buckets >=245 empty)
    if (tid < 246) starts_T[tid * SROW + p] = excl;
    __syncthreads();

    // ---- phase C: edge MLP, counting-sort packed pairs into LDS ----
#pragma unroll
    for (int r = 0; r < 7; ++r) {
        int idx = r * 256 + tid;
        if (idx >= gnum) continue;
        int g = gstart + idx;
        float4 e4 = ((const float4*)edges)[g];
        int4  s4 = ((const int4*)senders)[g];
        float ev[4] = {e4.x, e4.y, e4.z, e4.w};
        int   sv[4] = {s4.x, s4.y, s4.z, s4.w};
        int   rv[4] = {rv4[r].x, rv4[r].y, rv4[r].z, rv4[r].w};
        float nsv[4], nrv[4];
#pragma unroll
        for (int u = 0; u < 4; ++u) { nsv[u] = nodes[sv[u]]; nrv[u] = nodes[rv[u]]; }
#pragma unroll
        for (int u = 0; u < 4; ++u) {
            float nr = nrv[u], ns = nsv[u];
            float bs[5];
#pragma unroll
            for (int k = 0; k < 5; ++k) bs[k] = b_eb[k];
#pragma unroll
            for (int j = 0; j < 10; ++j) {
                float zl = fmaf(nr, w_pn1[j], fmaf(ns, w_pn1[10 + j], b_pn1[j]));
                float sz = selu2(zl);
#pragma unroll
                for (int k = 0; k < 5; ++k) bs[k] = fmaf(sz, W_eb[j * 5 + k], bs[k]);
            }
            float e = ev[u];
#pragma unroll
            for (int it = 0; it < 3; ++it) {
                float acc2 = b2e;
#pragma unroll
                for (int k = 0; k < 5; ++k) {
                    float tt = selu2(fmaf(e, w1r0[k], bs[k]));
                    acc2 = fmaf(tt, w2e[k], acc2);
                }
                e = acc2;
            }
            int bkt  = rv[u] >> BSHIFT;
            int slot = atomicAdd(&cursorS[bkt], 1);
            unsigned int pk = ((unsigned int)(rv[u] & (BWIDTH - 1)) << 16)
                            | (unsigned int)__half_as_ushort(__float2half_rn(e));
            staged[slot] = pk;
        }
    }
    __syncthreads();

    // ---- flush: contiguous, coalesced uint4 stores to private region ----
    const uint4* staged4 = (const uint4*)staged;
    uint4* dst = (uint4*)(pairs + (size_t)p * EPB);
    for (int i = tid; i < gnum; i += 256) dst[i] = staged4[i];
}

// gather: one 1024-thread block per bucket; walk per-block segments, LDS
// aggregate, node MLP, atomic-free parity-partials graph reduction.
__global__ __launch_bounds__(1024) void k_gather(
        const float* __restrict__ nodes, const int* __restrict__ graph_ids,
        const float* __restrict__ fw, const int* __restrict__ starts_T,
        const unsigned int* __restrict__ pairs, float* __restrict__ graph_acc,
        float* __restrict__ partials) {
    __shared__ float accf[BWIDTH];
    __shared__ int s0[SROW], s1[SROW];
    __shared__ float garr[32 * 11];
    int tid = threadIdx.x;
    int b   = blockIdx.x;

    accf[tid] = 0.0f; accf[1024 + tid] = 0.0f;
    if (tid < 352) garr[tid] = 0.0f;
    for (int i = tid; i < NPB; i += 1024) {
        s0[i] = starts_T[b * SROW + i];
        s1[i] = starts_T[(b + 1) * SROW + i];
    }
    __syncthreads();

    // ---- stream segments, accumulate into LDS ----
    int w = tid >> 6, lane = tid & 63;
    for (int p = w; p < NPB; p += 16) {
        int st = s0[p], en = s1[p];
        const unsigned int* seg = pairs + (size_t)p * EPB + st;
        int cnt = en - st;
        for (int i = lane; i < cnt; i += 64) {
            unsigned int pk = seg[i];
            atomicAdd(&accf[(pk >> 16) & (BWIDTH - 1)],
                      __half2float(__ushort_as_half((unsigned short)(pk & 0xffff))));
        }
    }
    __syncthreads();

    // ---- node MLP + graph reduction ----
    float w_pe1[5], b_pe1[5], pe_w2[50], pe_b2[10], W_nb[25], b_nb[5], w1r0n[5], w2n[5];
#pragma unroll
    for (int j = 0; j < 5; ++j) w_pe1[j] = fw[96 + j];
#pragma unroll
    for (int j = 0; j < 5; ++j) b_pe1[j] = fw[101 + j];
#pragma unroll
    for (int j = 0; j < 50; ++j) pe_w2[j] = fw[106 + j];
#pragma unroll
    for (int j = 0; j < 10; ++j) pe_b2[j] = fw[156 + j];
#pragma unroll
    for (int j = 0; j < 25; ++j) W_nb[j] = fw[166 + j];
#pragma unroll
    for (int j = 0; j < 5; ++j) b_nb[j] = fw[191 + j];
#pragma unroll
    for (int j = 0; j < 5; ++j) w1r0n[j] = fw[196 + j];
#pragma unroll
    for (int j = 0; j < 5; ++j) w2n[j] = fw[201 + j];
    float b2n = fw[206];

    int nodeBase = b << BSHIFT;
    int lastIdx  = nodeBase + BWIDTH;
    if (lastIdx > N_NODES_C) lastIdx = N_NODES_C;
    int gidBase = graph_ids[nodeBase];
    int gidEnd  = graph_ids[lastIdx - 1];

#pragma unroll
    for (int q = 0; q < 2; ++q) {
        int local = q * 1024 + tid;
        int i = nodeBase + local;
        bool valid = i < N_NODES_C;

        float s = accf[local];
        float t5[5];
#pragma unroll
        for (int k = 0; k < 5; ++k) t5[k] = selu2(fmaf(s, w_pe1[k], b_pe1[k]));
        float he[10];
#pragma unroll
        for (int m = 0; m < 10; ++m) {
            float a = pe_b2[m];
#pragma unroll
            for (int k = 0; k < 5; ++k) a = fmaf(t5[k], pe_w2[k * 10 + m], a);
            he[m] = a;
        }
        float bs[5];
#pragma unroll
        for (int k = 0; k < 5; ++k) {
            float a = b_nb[k];
#pragma unroll
            for (int t = 0; t < 5; ++t) a = fmaf(t5[t], W_nb[t * 5 + k], a);
            bs[k] = a;
        }
        float n = valid ? nodes[i] : 0.0f;
#pragma unroll
        for (int it = 0; it < 3; ++it) {
            float a = b2n;
#pragma unroll
            for (int k = 0; k < 5; ++k) {
                float tt = selu2(fmaf(n, w1r0n[k], bs[k]));
                a = fmaf(tt, w2n[k], a);
            }
            n = a;
        }

        int gid = valid ? graph_ids[i] : -1;
        if (!valid) {
            n = 0.0f;
#pragma unroll
            for (int m = 0; m < 10; ++m) he[m] = 0.0f;
        }

        int gid0 = __shfl(gid, 0, 64);
        bool allsame = __all(gid == gid0) && (gid0 >= 0);
        if (allsame) {
            float v = n;
#pragma unroll
            for (int off = 32; off > 0; off >>= 1) v += __shfl_down(v, off, 64);
            float vh[10];
#pragma unroll
            for (int m = 0; m < 10; ++m) {
                float ww = he[m];
#pragma unroll
                for (int off = 32; off > 0; off >>= 1) ww += __shfl_down(ww, off, 64);
                vh[m] = ww;
            }
            if ((tid & 63) == 0) {
                int off = gid0 - gidBase;
                if (off >= 0 && off < 32) {
                    atomicAdd(&garr[off * 11 + 0], v);
#pragma unroll
                    for (int m = 0; m < 10; ++m) atomicAdd(&garr[off * 11 + 1 + m], vh[m]);
                } else {
                    atomAddF(&graph_acc[gid0 * 11 + 0], v);
#pragma unroll
                    for (int m = 0; m < 10; ++m) atomAddF(&graph_acc[gid0 * 11 + 1 + m], vh[m]);
                }
            }
        } else if (valid) {
            int off = gid - gidBase;
            if (off >= 0 && off < 32) {
                atomicAdd(&garr[off * 11 + 0], n);
#pragma unroll
                for (int m = 0; m < 10; ++m) atomicAdd(&garr[off * 11 + 1 + m], he[m]);
            } else {
                atomAddF(&graph_acc[gid * 11 + 0], n);
#pragma unroll
                for (int m = 0; m < 10; ++m) atomAddF(&graph_acc[gid * 11 + 1 + m], he[m]);
            }
        }
    }
    __syncthreads();

    // plain-store partials: graph spans <=2 consecutive blocks -> parity slot
    int ngl = gidEnd - gidBase + 1;
    if (ngl > 32) ngl = 32;            // overflow handled by global-atomic path
    int par = (b & 1) * 11000;
    for (int t = tid; t < ngl * 11; t += 1024) {
        int off = t / 11, f = t - off * 11;
        partials[par + (gidBase + off) * 11 + f] = garr[t];
    }
}

// ---------------- fallback path (ws too small) ----------------

__global__ __launch_bounds__(256) void k_zero(float* __restrict__ ws, int len4) {
    int i = blockIdx.x * 256 + threadIdx.x;
    if (i < len4) ((float4*)ws)[i] = make_float4(0.f, 0.f, 0.f, 0.f);
}

__global__ __launch_bounds__(256) void k_edges(
        const float* __restrict__ nodes, const float* __restrict__ edges,
        const int* __restrict__ senders, const int* __restrict__ receivers,
        const float* __restrict__ fw, float* __restrict__ node_acc) {
    float w_pn1[20], b_pn1[10], W_eb[50], b_eb[5], w1r0[5], w2e[5];
#pragma unroll
    for (int j = 0; j < 20; ++j) w_pn1[j] = fw[j];
#pragma unroll
    for (int j = 0; j < 10; ++j) b_pn1[j] = fw[20 + j];
#pragma unroll
    for (int j = 0; j < 50; ++j) W_eb[j] = fw[30 + j];
#pragma unroll
    for (int j = 0; j < 5; ++j) b_eb[j] = fw[80 + j];
#pragma unroll
    for (int j = 0; j < 5; ++j) w1r0[j] = fw[85 + j];
#pragma unroll
    for (int j = 0; j < 5; ++j) w2e[j] = fw[90 + j];
    float b2e = fw[95];

    int g = blockIdx.x * 256 + threadIdx.x;
    if (g >= NGROUPS_C) return;

    float4 e4 = ((const float4*)edges)[g];
    int4  s4 = ((const int4*)senders)[g];
    int4  r4 = ((const int4*)receivers)[g];
    float ev[4] = {e4.x, e4.y, e4.z, e4.w};
    int   sv[4] = {s4.x, s4.y, s4.z, s4.w};
    int   rv[4] = {r4.x, r4.y, r4.z, r4.w};
    float nsv[4], nrv[4];
#pragma unroll
    for (int u = 0; u < 4; ++u) { nsv[u] = nodes[sv[u]]; nrv[u] = nodes[rv[u]]; }
#pragma unroll
    for (int u = 0; u < 4; ++u) {
        float nr = nrv[u], ns = nsv[u];
        float bs[5];
#pragma unroll
        for (int k = 0; k < 5; ++k) bs[k] = b_eb[k];
#pragma unroll
        for (int j = 0; j < 10; ++j) {
            float zl = fmaf(nr, w_pn1[j], fmaf(ns, w_pn1[10 + j], b_pn1[j]));
            float sz = selu2(zl);
#pragma unroll
            for (int k = 0; k < 5; ++k) bs[k] = fmaf(sz, W_eb[j * 5 + k], bs[k]);
        }
        float e = ev[u];
#pragma unroll
        for (int it = 0; it < 3; ++it) {
            float acc2 = b2e;
#pragma unroll
            for (int k = 0; k < 5; ++k) {
                float tt = selu2(fmaf(e, w1r0[k], bs[k]));
                acc2 = fmaf(tt, w2e[k], acc2);
            }
            e = acc2;
        }
        atomAddF(&node_acc[rv[u]], e);
    }
}

__global__ __launch_bounds__(256) void k_nodes(
        const float* __restrict__ nodes, const int* __restrict__ graph_ids,
        const float* __restrict__ fw, const float* __restrict__ node_acc,
        float* __restrict__ graph_acc) {
    float w_pe1[5], b_pe1[5], pe_w2[50], pe_b2[10], W_nb[25], b_nb[5], w1r0n[5], w2n[5];
#pragma unroll
    for (int j = 0; j < 5; ++j) w_pe1[j] = fw[96 + j];
#pragma unroll
    for (int j = 0; j < 5; ++j) b_pe1[j] = fw[101 + j];
#pragma unroll
    for (int j = 0; j < 50; ++j) pe_w2[j] = fw[106 + j];
#pragma unroll
    for (int j = 0; j < 10; ++j) pe_b2[j] = fw[156 + j];
#pragma unroll
    for (int j = 0; j < 25; ++j) W_nb[j] = fw[166 + j];
#pragma unroll
    for (int j = 0; j < 5; ++j) b_nb[j] = fw[191 + j];
#pragma unroll
    for (int j = 0; j < 5; ++j) w1r0n[j] = fw[196 + j];
#pragma unroll
    for (int j = 0; j < 5; ++j) w2n[j] = fw[201 + j];
    float b2n = fw[206];

    int i = blockIdx.x * 256 + threadIdx.x;
    bool valid = i < N_NODES_C;
    int ii = valid ? i : (N_NODES_C - 1);

    float s = node_acc[ii];
    float t5[5];
#pragma unroll
    for (int k = 0; k < 5; ++k) t5[k] = selu2(fmaf(s, w_pe1[k], b_pe1[k]));
    float he[10];
#pragma unroll
    for (int m = 0; m < 10; ++m) {
        float a = pe_b2[m];
#pragma unroll
        for (int k = 0; k < 5; ++k) a = fmaf(t5[k], pe_w2[k * 10 + m], a);
        he[m] = a;
    }
    float bs[5];
#pragma unroll
    for (int k = 0; k < 5; ++k) {
        float a = b_nb[k];
#pragma unroll
        for (int t = 0; t < 5; ++t) a = fmaf(t5[t], W_nb[t * 5 + k], a);
        bs[k] = a;
    }
    float n = nodes[ii];
#pragma unroll
    for (int it = 0; it < 3; ++it) {
        float a = b2n;
#pragma unroll
        for (int k = 0; k < 5; ++k) {
            float tt = selu2(fmaf(n, w1r0n[k], bs[k]));
            a = fmaf(tt, w2n[k], a);
        }
        n = a;
    }

    int gid = valid ? graph_ids[ii] : -1;
    if (!valid) {
        n = 0.0f;
#pragma unroll
        for (int m = 0; m < 10; ++m) he[m] = 0.0f;
    }

    int gid0 = __shfl(gid, 0, 64);
    bool allsame = __all(gid == gid0) && (gid0 >= 0);
    if (allsame) {
        float v = n;
#pragma unroll
        for (int off = 32; off > 0; off >>= 1) v += __shfl_down(v, off, 64);
        float vh[10];
#pragma unroll
        for (int m = 0; m < 10; ++m) {
            float ww = he[m];
#pragma unroll
            for (int off = 32; off > 0; off >>= 1) ww += __shfl_down(ww, off, 64);
            vh[m] = ww;
        }
        if ((threadIdx.x & 63) == 0) {
            atomAddF(&graph_acc[gid0 * 11 + 0], v);
#pragma unroll
            for (int m = 0; m < 10; ++m) atomAddF(&graph_acc[gid0 * 11 + 1 + m], vh[m]);
        }
    } else if (valid) {
        atomAddF(&graph_acc[gid * 11 + 0], n);
#pragma unroll
        for (int m = 0; m < 10; ++m) atomAddF(&graph_acc[gid * 11 + 1 + m], he[m]);
    }
}

// ---------------- launch ----------------

extern "C" void kernel_launch(void* const* d_in, const int* in_sizes, int n_in,
                              void* d_out, int out_size, void* d_ws, size_t ws_size,
                              hipStream_t stream) {
    const float* nodes     = (const float*)d_in[0];
    const float* edges     = (const float*)d_in[1];
    const int*   senders   = (const int*)d_in[2];
    const int*   receivers = (const int*)d_in[3];
    const int*   graph_ids = (const int*)d_in[4];
    const float* pn_w1 = (const float*)d_in[6];
    const float* pn_b1 = (const float*)d_in[7];
    const float* pn_w2 = (const float*)d_in[8];
    const float* pn_b2 = (const float*)d_in[9];
    const float* ue_w1 = (const float*)d_in[10];
    const float* ue_b1 = (const float*)d_in[11];
    const float* ue_w2 = (const float*)d_in[12];
    const float* ue_b2 = (const float*)d_in[13];
    const float* pe_w1 = (const float*)d_in[14];
    const float* pe_b1 = (const float*)d_in[15];
    const float* pe_w2 = (const float*)d_in[16];
    const float* pe_b2 = (const float*)d_in[17];
    const float* un_w1 = (const float*)d_in[18];
    const float* un_b1 = (const float*)d_in[19];
    const float* un_w2 = (const float*)d_in[20];
    const float* un_b2 = (const float*)d_in[21];
    const float* pr_w1 = (const float*)d_in[22];
    const float* pr_b1 = (const float*)d_in[23];
    const float* pr_w2 = (const float*)d_in[24];
    const float* pr_b2 = (const float*)d_in[25];

    float* ws        = (float*)d_ws;
    float* graph_acc = ws + GRAPH_ACC_OFF;
    float* partials  = ws + PARTIALS_OFF;
    float* fw        = ws + FW_OFF;
    float* outp      = (float*)d_out;

    if (ws_size >= (size_t)WS_WORDS_NEEDED * 4) {
        int* starts_T        = (int*)ws + STARTS_OFF;
        unsigned int* pairs  = (unsigned int*)ws + PAIRS_OFF;

        hipLaunchKernelGGL(k_init, dim3((ZERO_HEAD + 255) / 256), dim3(256), 0, stream, ws,
                           pn_w1, pn_b1, pn_w2, pn_b2, ue_w1, ue_b1, ue_w2, ue_b2,
                           pe_w1, pe_b1, pe_w2, pe_b2, un_w1, un_b1, un_w2, un_b2);
        hipLaunchKernelGGL(k_part, dim3(NPB), dim3(256), 0, stream,
                           nodes, edges, senders, receivers, fw, starts_T, pairs);
        hipLaunchKernelGGL(k_gather, dim3(NBKT), dim3(1024), 0, stream,
                           nodes, graph_ids, fw, starts_T, pairs, graph_acc, partials);
        hipLaunchKernelGGL(k_final, dim3((N_GRAPHS_C + 255) / 256), dim3(256), 0, stream,
                           graph_acc, partials, pr_w1, pr_b1, pr_w2, pr_b2, outp);
    } else {
        float* node_acc = ws + OLD_NODE_ACC_OFF;
        int len4 = OLD_ZERO_WORDS / 4;
        hipLaunchKernelGGL(k_zero, dim3((len4 + 255) / 256), dim3(256), 0, stream, ws, len4);
        hipLaunchKernelGGL(k_fuse, dim3(1), dim3(64), 0, stream,
                           pn_w1, pn_b1, pn_w2, pn_b2, ue_w1, ue_b1, ue_w2, ue_b2,
                           pe_w1, pe_b1, pe_w2, pe_b2, un_w1, un_b1, un_w2, un_b2, fw);
        hipLaunchKernelGGL(k_edges, dim3((NGROUPS_C + 255) / 256), dim3(256), 0, stream,
                           nodes, edges, senders, receivers, fw, node_acc);
        hipLaunchKernelGGL(k_nodes, dim3((N_NODES_C + 255) / 256), dim3(256), 0, stream,
                           nodes, graph_ids, fw, node_acc, graph_acc);
        hipLaunchKernelGGL(k_final, dim3((N_GRAPHS_C + 255) / 256), dim3(256), 0, stream,
                           graph_acc, partials, pr_w1, pr_b1, pr_w2, pr_b2, outp);
    }
}

// Round 8
// 315.510 us; speedup vs baseline: 1.1426x; 1.0316x over previous
//
#include <hip/hip_runtime.h>
#include <hip/hip_fp16.h>
#include <math.h>

#define N_NODES_C  500000
#define N_EDGES_C  8000000
#define N_GRAPHS_C 1000
#define NGROUPS_C  (N_EDGES_C / 4)     // 2,000,000 float4-groups

#define BSHIFT  11                     // bucket = recv >> 11
#define BWIDTH  2048
#define NBKT    245                    // ceil(500000 / 2048)

#define EPB     8192                   // edges per part-block (32KB staged)
#define GPB     (EPB / 4)              // 2048 groups per part-block
#define NPB     ((NGROUPS_C + GPB - 1) / GPB)   // 977 part-blocks
#define SROW    992                    // starts_T row stride (ints), >= NPB

// ---- workspace layout (32-bit word offsets) ----
#define GRAPH_ACC_OFF 0                          // 11000 floats
#define PARTIALS_OFF  11008                      // 2*11000 floats
#define FW_OFF        33024                      // 207 floats fused weights
#define STARTS_OFF    33280                      // 246 * SROW ints
#define PAIRS_OFF     (STARTS_OFF + 246 * SROW)  // 277312; 16B aligned
#define WS_WORDS_NEEDED (PAIRS_OFF + NPB * EPB)
#define ZERO_HEAD     33024                      // graph_acc + partials
// ---- fallback layout ----
#define OLD_NODE_ACC_OFF 33536
#define OLD_ZERO_WORDS   (OLD_NODE_ACC_OFF + N_NODES_C)

#define LOG2E_F 1.4426950408889634f

// fused-weight layout inside fw[]; (L) = pre-scaled by log2(e):
// 0:w_pn1[20](L) 20:b_pn1[10](L) 30:W_eb[50](L) 80:b_eb[5](L) 85:w1r0_e[5](L)
// 90:w2_e[5] 95:b2_e
// 96:w_pe1[5](L) 101:b_pe1[5](L) 106:pe_w2[50] 156:pe_b2[10]
// 166:W_nb[25](L) 191:b_nb[5](L) 196:w1r0_n[5](L) 201:w2_n[5] 206:b2_n

__device__ __forceinline__ float selu2(float xl) {
    const float C1 = 0.7282901039f;        // 1.0507009873554805 * ln(2)
    const float C2 = 1.7580993408473766f;  // scale * alpha
    float e = __builtin_amdgcn_exp2f(xl);
    float neg = fmaf(C2, e, -C2);
    return xl > 0.0f ? C1 * xl : neg;
}

__device__ __forceinline__ float selu_f(float x) {
    const float scale = 1.0507009873554805f;
    const float sa    = 1.0507009873554805f * 1.6732632423543772f;
    float neg = sa * (__expf(x) - 1.0f);
    return x > 0.0f ? scale * x : neg;
}

__device__ __forceinline__ void atomAddF(float* p, float v) {
    __hip_atomic_fetch_add(p, v, __ATOMIC_RELAXED, __HIP_MEMORY_SCOPE_AGENT);
}

__device__ __forceinline__ void fuse_weights(
        int t,
        const float* __restrict__ pn_w1, const float* __restrict__ pn_b1,
        const float* __restrict__ pn_w2, const float* __restrict__ pn_b2,
        const float* __restrict__ ue_w1, const float* __restrict__ ue_b1,
        const float* __restrict__ ue_w2, const float* __restrict__ ue_b2,
        const float* __restrict__ pe_w1, const float* __restrict__ pe_b1,
        const float* __restrict__ pe_w2, const float* __restrict__ pe_b2,
        const float* __restrict__ un_w1, const float* __restrict__ un_b1,
        const float* __restrict__ un_w2, const float* __restrict__ un_b2,
        float* __restrict__ fw) {
    const float L = LOG2E_F;
    if (t < 20) fw[0 + t] = pn_w1[t] * L;
    if (t < 10) fw[20 + t] = pn_b1[t] * L;
    if (t < 50) {
        int j = t / 5, k = t % 5;
        float s = 0.0f;
        for (int m = 0; m < 10; ++m) s += pn_w2[j * 10 + m] * ue_w1[(1 + m) * 5 + k];
        fw[30 + t] = s * L;
    }
    if (t < 5) {
        float s = ue_b1[t];
        for (int m = 0; m < 10; ++m) s += pn_b2[m] * ue_w1[(1 + m) * 5 + t];
        fw[80 + t] = s * L;
    }
    if (t < 5)  fw[85 + t]  = ue_w1[t] * L;
    if (t < 5)  fw[90 + t]  = ue_w2[t];
    if (t == 0) fw[95]      = ue_b2[0];
    if (t < 5)  fw[96 + t]  = pe_w1[t] * L;
    if (t < 5)  fw[101 + t] = pe_b1[t] * L;
    if (t < 50) fw[106 + t] = pe_w2[t];
    if (t < 10) fw[156 + t] = pe_b2[t];
    if (t < 25) {
        int j = t / 5, k = t % 5;
        float s = 0.0f;
        for (int m = 0; m < 10; ++m) s += pe_w2[j * 10 + m] * un_w1[(1 + m) * 5 + k];
        fw[166 + t] = s * L;
    }
    if (t < 5) {
        float s = un_b1[t];
        for (int m = 0; m < 10; ++m) s += pe_b2[m] * un_w1[(1 + m) * 5 + t];
        fw[191 + t] = s * L;
    }
    if (t < 5)  fw[196 + t] = un_w1[t] * L;
    if (t < 5)  fw[201 + t] = un_w2[t];
    if (t == 0) fw[206]     = un_b2[0];
}

// init: zero graph_acc+partials; block 0 builds fused weights
__global__ __launch_bounds__(256) void k_init(
        float* __restrict__ ws,
        const float* pn_w1, const float* pn_b1, const float* pn_w2, const float* pn_b2,
        const float* ue_w1, const float* ue_b1, const float* ue_w2, const float* ue_b2,
        const float* pe_w1, const float* pe_b1, const float* pe_w2, const float* pe_b2,
        const float* un_w1, const float* un_b1, const float* un_w2, const float* un_b2) {
    int i = blockIdx.x * 256 + threadIdx.x;
    if (i < ZERO_HEAD) ws[i] = 0.0f;
    if (blockIdx.x == 0)
        fuse_weights(threadIdx.x, pn_w1, pn_b1, pn_w2, pn_b2, ue_w1, ue_b1, ue_w2, ue_b2,
                     pe_w1, pe_b1, pe_w2, pe_b2, un_w1, un_b1, un_w2, un_b2, ws + FW_OFF);
}

__global__ void k_fuse(const float* pn_w1, const float* pn_b1, const float* pn_w2, const float* pn_b2,
                       const float* ue_w1, const float* ue_b1, const float* ue_w2, const float* ue_b2,
                       const float* pe_w1, const float* pe_b1, const float* pe_w2, const float* pe_b2,
                       const float* un_w1, const float* un_b1, const float* un_w2, const float* un_b2,
                       float* fw) {
    fuse_weights(threadIdx.x, pn_w1, pn_b1, pn_w2, pn_b2, ue_w1, ue_b1, ue_w2, ue_b2,
                 pe_w1, pe_b1, pe_w2, pe_b2, un_w1, un_b1, un_w2, un_b2, fw);
}

__global__ void k_final(const float* __restrict__ graph_acc,
                        const float* __restrict__ partials,
                        const float* __restrict__ pr_w1, const float* __restrict__ pr_b1,
                        const float* __restrict__ pr_w2, const float* __restrict__ pr_b2,
                        float* __restrict__ out) {
    int g = blockIdx.x * blockDim.x + threadIdx.x;
    if (g >= N_GRAPHS_C) return;
    float gv[11];
#pragma unroll
    for (int f = 0; f < 11; ++f)
        gv[f] = graph_acc[g * 11 + f] + partials[g * 11 + f] + partials[11000 + g * 11 + f];
    float h[10];
#pragma unroll
    for (int j = 0; j < 10; ++j) {
        float z = pr_b1[j];
#pragma unroll
        for (int f = 0; f < 11; ++f) z = fmaf(gv[f], pr_w1[f * 10 + j], z);
        h[j] = selu_f(z);
    }
    float o[10];
    float mx = -1e30f;
#pragma unroll
    for (int j = 0; j < 10; ++j) {
        float z = pr_b2[j];
#pragma unroll
        for (int m = 0; m < 10; ++m) z = fmaf(h[m], pr_w2[m * 10 + j], z);
        o[j] = z;
        mx = fmaxf(mx, z);
    }
    float sum = 0.0f;
#pragma unroll
    for (int j = 0; j < 10; ++j) { o[j] = __expf(o[j] - mx); sum += o[j]; }
    float inv = 1.0f / sum;
#pragma unroll
    for (int j = 0; j < 10; ++j) out[g * 10 + j] = o[j] * inv;
}

// ---------------- main path ----------------

// partition: edge MLP + block-local counting sort, contiguous uint4 flush.
// Phase C is software-pipelined 2-deep: edges/senders loaded 2 iters ahead,
// node gathers issued 1 full iter (one MLP body) before use.
__global__ __launch_bounds__(256) void k_part(
        const float* __restrict__ nodes, const float* __restrict__ edges,
        const int* __restrict__ senders, const int* __restrict__ receivers,
        const float* __restrict__ fw, int* __restrict__ starts_T,
        unsigned int* __restrict__ pairs) {
    __shared__ int hist[256];
    __shared__ int cursorS[256];
    __shared__ unsigned int staged[EPB];   // 32 KB

    int tid = threadIdx.x;
    int p   = blockIdx.x;
    int gstart = p * GPB;
    int gnum   = NGROUPS_C - gstart;
    if (gnum > GPB) gnum = GPB;

    // ---- weights (wave-uniform -> scalar regs); layer-1 in log2 domain ----
    float w_pn1[20], b_pn1[10], W_eb[50], b_eb[5], w1r0[5], w2e[5];
#pragma unroll
    for (int j = 0; j < 20; ++j) w_pn1[j] = fw[j];
#pragma unroll
    for (int j = 0; j < 10; ++j) b_pn1[j] = fw[20 + j];
#pragma unroll
    for (int j = 0; j < 50; ++j) W_eb[j] = fw[30 + j];
#pragma unroll
    for (int j = 0; j < 5; ++j) b_eb[j] = fw[80 + j];
#pragma unroll
    for (int j = 0; j < 5; ++j) w1r0[j] = fw[85 + j];
#pragma unroll
    for (int j = 0; j < 5; ++j) w2e[j] = fw[90 + j];
    float b2e = fw[95];

    hist[tid] = 0;
    __syncthreads();

    // ---- phase A: load receivers (kept in regs, clamped-safe), histogram ----
    int4 rv4[8];
#pragma unroll
    for (int r = 0; r < 8; ++r) {
        int idx = r * 256 + tid;
        int gi  = gstart + (idx < gnum ? idx : 0);
        rv4[r] = ((const int4*)receivers)[gi];
        if (idx < gnum) {
            atomicAdd(&hist[rv4[r].x >> BSHIFT], 1);
            atomicAdd(&hist[rv4[r].y >> BSHIFT], 1);
            atomicAdd(&hist[rv4[r].z >> BSHIFT], 1);
            atomicAdd(&hist[rv4[r].w >> BSHIFT], 1);
        }
    }
    __syncthreads();

    // ---- inclusive scan over 256 buckets (Hillis-Steele) ----
    int orig = hist[tid];
    int val  = orig;
    for (int d = 1; d < 256; d <<= 1) {
        int add = (tid >= d) ? hist[tid - d] : 0;
        __syncthreads();
        if (tid >= d) { val += add; hist[tid] = val; }
        __syncthreads();
    }
    int excl = val - orig;
    cursorS[tid] = excl;
    if (tid < 246) starts_T[tid * SROW + p] = excl;
    __syncthreads();

    // ---- phase C: 2-deep pipelined edge MLP + counting sort into LDS ----
    float4 e4buf[2];
    int4   s4buf[2];
    float  nsb[2][4], nrb[2][4];

    // prologue: load es[0]; gather nodes[0]; load es[1]
    {
        int gi0 = gstart + (tid < gnum ? tid : 0);
        e4buf[0] = ((const float4*)edges)[gi0];
        s4buf[0] = ((const int4*)senders)[gi0];
        nsb[0][0] = nodes[s4buf[0].x]; nsb[0][1] = nodes[s4buf[0].y];
        nsb[0][2] = nodes[s4buf[0].z]; nsb[0][3] = nodes[s4buf[0].w];
        nrb[0][0] = nodes[rv4[0].x];   nrb[0][1] = nodes[rv4[0].y];
        nrb[0][2] = nodes[rv4[0].z];   nrb[0][3] = nodes[rv4[0].w];
        int idx1 = 256 + tid;
        int gi1 = gstart + (idx1 < gnum ? idx1 : 0);
        e4buf[1] = ((const float4*)edges)[gi1];
        s4buf[1] = ((const int4*)senders)[gi1];
    }

#pragma unroll
    for (int r = 0; r < 8; ++r) {
        const int pb = r & 1;
        // consume current e4 before its slot is reused
        float ev[4] = {e4buf[pb].x, e4buf[pb].y, e4buf[pb].z, e4buf[pb].w};
        int   rv[4] = {rv4[r].x, rv4[r].y, rv4[r].z, rv4[r].w};
        float nsv[4] = {nsb[pb][0], nsb[pb][1], nsb[pb][2], nsb[pb][3]};
        float nrv[4] = {nrb[pb][0], nrb[pb][1], nrb[pb][2], nrb[pb][3]};

        // prefetch es[r+2] into slot pb (e4/s4[r] consumed above / below)
        if (r + 2 < 8) {
            int idx = (r + 2) * 256 + tid;
            int gi  = gstart + (idx < gnum ? idx : 0);
            e4buf[pb] = ((const float4*)edges)[gi];
            // keep s4buf[pb] until after gathers below? s4[r] gathers were
            // issued LAST iteration; safe to overwrite now.
            s4buf[pb] = ((const int4*)senders)[gi];
        }
        // issue node gathers for r+1 (uses s4buf[!pb] loaded 1 iter ago)
        if (r + 1 < 8) {
            const int qb = pb ^ 1;
            nsb[qb][0] = nodes[s4buf[qb].x]; nsb[qb][1] = nodes[s4buf[qb].y];
            nsb[qb][2] = nodes[s4buf[qb].z]; nsb[qb][3] = nodes[s4buf[qb].w];
            nrb[qb][0] = nodes[rv4[r + 1].x]; nrb[qb][1] = nodes[rv4[r + 1].y];
            nrb[qb][2] = nodes[rv4[r + 1].z]; nrb[qb][3] = nodes[rv4[r + 1].w];
        }

        bool validr = (r * 256 + tid) < gnum;
#pragma unroll
        for (int u = 0; u < 4; ++u) {
            float nr = nrv[u], ns = nsv[u];
            float bs[5];
#pragma unroll
            for (int k = 0; k < 5; ++k) bs[k] = b_eb[k];
#pragma unroll
            for (int j = 0; j < 10; ++j) {
                float zl = fmaf(nr, w_pn1[j], fmaf(ns, w_pn1[10 + j], b_pn1[j]));
                float sz = selu2(zl);
#pragma unroll
                for (int k = 0; k < 5; ++k) bs[k] = fmaf(sz, W_eb[j * 5 + k], bs[k]);
            }
            float e = ev[u];
#pragma unroll
            for (int it = 0; it < 3; ++it) {
                float acc2 = b2e;
#pragma unroll
                for (int k = 0; k < 5; ++k) {
                    float tt = selu2(fmaf(e, w1r0[k], bs[k]));
                    acc2 = fmaf(tt, w2e[k], acc2);
                }
                e = acc2;
            }
            if (validr) {
                int bkt  = rv[u] >> BSHIFT;
                int slot = atomicAdd(&cursorS[bkt], 1);
                unsigned int pk = ((unsigned int)(rv[u] & (BWIDTH - 1)) << 16)
                                | (unsigned int)__half_as_ushort(__float2half_rn(e));
                staged[slot] = pk;
            }
        }
    }
    __syncthreads();

    // ---- flush: contiguous, coalesced uint4 stores to private region ----
    const uint4* staged4 = (const uint4*)staged;
    uint4* dst = (uint4*)(pairs + (size_t)p * EPB);
    for (int i = tid; i < gnum; i += 256) dst[i] = staged4[i];
}

// gather: one 1024-thread block per bucket; walk per-block segments, LDS
// aggregate, node MLP, atomic-free parity-partials graph reduction.
__global__ __launch_bounds__(1024) void k_gather(
        const float* __restrict__ nodes, const int* __restrict__ graph_ids,
        const float* __restrict__ fw, const int* __restrict__ starts_T,
        const unsigned int* __restrict__ pairs, float* __restrict__ graph_acc,
        float* __restrict__ partials) {
    __shared__ float accf[BWIDTH];
    __shared__ int s0[SROW], s1[SROW];
    __shared__ float garr[32 * 11];
    int tid = threadIdx.x;
    int b   = blockIdx.x;

    accf[tid] = 0.0f; accf[1024 + tid] = 0.0f;
    if (tid < 352) garr[tid] = 0.0f;
    for (int i = tid; i < NPB; i += 1024) {
        s0[i] = starts_T[b * SROW + i];
        s1[i] = starts_T[(b + 1) * SROW + i];
    }
    __syncthreads();

    // ---- stream segments, accumulate into LDS ----
    int w = tid >> 6, lane = tid & 63;
    for (int p = w; p < NPB; p += 16) {
        int st = s0[p], en = s1[p];
        const unsigned int* seg = pairs + (size_t)p * EPB + st;
        int cnt = en - st;
        for (int i = lane; i < cnt; i += 64) {
            unsigned int pk = seg[i];
            atomicAdd(&accf[(pk >> 16) & (BWIDTH - 1)],
                      __half2float(__ushort_as_half((unsigned short)(pk & 0xffff))));
        }
    }
    __syncthreads();

    // ---- node MLP + graph reduction ----
    float w_pe1[5], b_pe1[5], pe_w2[50], pe_b2[10], W_nb[25], b_nb[5], w1r0n[5], w2n[5];
#pragma unroll
    for (int j = 0; j < 5; ++j) w_pe1[j] = fw[96 + j];
#pragma unroll
    for (int j = 0; j < 5; ++j) b_pe1[j] = fw[101 + j];
#pragma unroll
    for (int j = 0; j < 50; ++j) pe_w2[j] = fw[106 + j];
#pragma unroll
    for (int j = 0; j < 10; ++j) pe_b2[j] = fw[156 + j];
#pragma unroll
    for (int j = 0; j < 25; ++j) W_nb[j] = fw[166 + j];
#pragma unroll
    for (int j = 0; j < 5; ++j) b_nb[j] = fw[191 + j];
#pragma unroll
    for (int j = 0; j < 5; ++j) w1r0n[j] = fw[196 + j];
#pragma unroll
    for (int j = 0; j < 5; ++j) w2n[j] = fw[201 + j];
    float b2n = fw[206];

    int nodeBase = b << BSHIFT;
    int lastIdx  = nodeBase + BWIDTH;
    if (lastIdx > N_NODES_C) lastIdx = N_NODES_C;
    int gidBase = graph_ids[nodeBase];
    int gidEnd  = graph_ids[lastIdx - 1];

#pragma unroll
    for (int q = 0; q < 2; ++q) {
        int local = q * 1024 + tid;
        int i = nodeBase + local;
        bool valid = i < N_NODES_C;

        float s = accf[local];
        float t5[5];
#pragma unroll
        for (int k = 0; k < 5; ++k) t5[k] = selu2(fmaf(s, w_pe1[k], b_pe1[k]));
        float he[10];
#pragma unroll
        for (int m = 0; m < 10; ++m) {
            float a = pe_b2[m];
#pragma unroll
            for (int k = 0; k < 5; ++k) a = fmaf(t5[k], pe_w2[k * 10 + m], a);
            he[m] = a;
        }
        float bs[5];
#pragma unroll
        for (int k = 0; k < 5; ++k) {
            float a = b_nb[k];
#pragma unroll
            for (int t = 0; t < 5; ++t) a = fmaf(t5[t], W_nb[t * 5 + k], a);
            bs[k] = a;
        }
        float n = valid ? nodes[i] : 0.0f;
#pragma unroll
        for (int it = 0; it < 3; ++it) {
            float a = b2n;
#pragma unroll
            for (int k = 0; k < 5; ++k) {
                float tt = selu2(fmaf(n, w1r0n[k], bs[k]));
                a = fmaf(tt, w2n[k], a);
            }
            n = a;
        }

        int gid = valid ? graph_ids[i] : -1;
        if (!valid) {
            n = 0.0f;
#pragma unroll
            for (int m = 0; m < 10; ++m) he[m] = 0.0f;
        }

        int gid0 = __shfl(gid, 0, 64);
        bool allsame = __all(gid == gid0) && (gid0 >= 0);
        if (allsame) {
            float v = n;
#pragma unroll
            for (int off = 32; off > 0; off >>= 1) v += __shfl_down(v, off, 64);
            float vh[10];
#pragma unroll
            for (int m = 0; m < 10; ++m) {
                float ww = he[m];
#pragma unroll
                for (int off = 32; off > 0; off >>= 1) ww += __shfl_down(ww, off, 64);
                vh[m] = ww;
            }
            if ((tid & 63) == 0) {
                int off = gid0 - gidBase;
                if (off >= 0 && off < 32) {
                    atomicAdd(&garr[off * 11 + 0], v);
#pragma unroll
                    for (int m = 0; m < 10; ++m) atomicAdd(&garr[off * 11 + 1 + m], vh[m]);
                } else {
                    atomAddF(&graph_acc[gid0 * 11 + 0], v);
#pragma unroll
                    for (int m = 0; m < 10; ++m) atomAddF(&graph_acc[gid0 * 11 + 1 + m], vh[m]);
                }
            }
        } else if (valid) {
            int off = gid - gidBase;
            if (off >= 0 && off < 32) {
                atomicAdd(&garr[off * 11 + 0], n);
#pragma unroll
                for (int m = 0; m < 10; ++m) atomicAdd(&garr[off * 11 + 1 + m], he[m]);
            } else {
                atomAddF(&graph_acc[gid * 11 + 0], n);
#pragma unroll
                for (int m = 0; m < 10; ++m) atomAddF(&graph_acc[gid * 11 + 1 + m], he[m]);
            }
        }
    }
    __syncthreads();

    // plain-store partials: graph spans <=2 consecutive blocks -> parity slot
    int ngl = gidEnd - gidBase + 1;
    if (ngl > 32) ngl = 32;            // overflow handled by global-atomic path
    int par = (b & 1) * 11000;
    for (int t = tid; t < ngl * 11; t += 1024) {
        int off = t / 11, f = t - off * 11;
        partials[par + (gidBase + off) * 11 + f] = garr[t];
    }
}

// ---------------- fallback path (ws too small) ----------------

__global__ __launch_bounds__(256) void k_zero(float* __restrict__ ws, int len4) {
    int i = blockIdx.x * 256 + threadIdx.x;
    if (i < len4) ((float4*)ws)[i] = make_float4(0.f, 0.f, 0.f, 0.f);
}

__global__ __launch_bounds__(256) void k_edges(
        const float* __restrict__ nodes, const float* __restrict__ edges,
        const int* __restrict__ senders, const int* __restrict__ receivers,
        const float* __restrict__ fw, float* __restrict__ node_acc) {
    float w_pn1[20], b_pn1[10], W_eb[50], b_eb[5], w1r0[5], w2e[5];
#pragma unroll
    for (int j = 0; j < 20; ++j) w_pn1[j] = fw[j];
#pragma unroll
    for (int j = 0; j < 10; ++j) b_pn1[j] = fw[20 + j];
#pragma unroll
    for (int j = 0; j < 50; ++j) W_eb[j] = fw[30 + j];
#pragma unroll
    for (int j = 0; j < 5; ++j) b_eb[j] = fw[80 + j];
#pragma unroll
    for (int j = 0; j < 5; ++j) w1r0[j] = fw[85 + j];
#pragma unroll
    for (int j = 0; j < 5; ++j) w2e[j] = fw[90 + j];
    float b2e = fw[95];

    int g = blockIdx.x * 256 + threadIdx.x;
    if (g >= NGROUPS_C) return;

    float4 e4 = ((const float4*)edges)[g];
    int4  s4 = ((const int4*)senders)[g];
    int4  r4 = ((const int4*)receivers)[g];
    float ev[4] = {e4.x, e4.y, e4.z, e4.w};
    int   sv[4] = {s4.x, s4.y, s4.z, s4.w};
    int   rv[4] = {r4.x, r4.y, r4.z, r4.w};
    float nsv[4], nrv[4];
#pragma unroll
    for (int u = 0; u < 4; ++u) { nsv[u] = nodes[sv[u]]; nrv[u] = nodes[rv[u]]; }
#pragma unroll
    for (int u = 0; u < 4; ++u) {
        float nr = nrv[u], ns = nsv[u];
        float bs[5];
#pragma unroll
        for (int k = 0; k < 5; ++k) bs[k] = b_eb[k];
#pragma unroll
        for (int j = 0; j < 10; ++j) {
            float zl = fmaf(nr, w_pn1[j], fmaf(ns, w_pn1[10 + j], b_pn1[j]));
            float sz = selu2(zl);
#pragma unroll
            for (int k = 0; k < 5; ++k) bs[k] = fmaf(sz, W_eb[j * 5 + k], bs[k]);
        }
        float e = ev[u];
#pragma unroll
        for (int it = 0; it < 3; ++it) {
            float acc2 = b2e;
#pragma unroll
            for (int k = 0; k < 5; ++k) {
                float tt = selu2(fmaf(e, w1r0[k], bs[k]));
                acc2 = fmaf(tt, w2e[k], acc2);
            }
            e = acc2;
        }
        atomAddF(&node_acc[rv[u]], e);
    }
}

__global__ __launch_bounds__(256) void k_nodes(
        const float* __restrict__ nodes, const int* __restrict__ graph_ids,
        const float* __restrict__ fw, const float* __restrict__ node_acc,
        float* __restrict__ graph_acc) {
    float w_pe1[5], b_pe1[5], pe_w2[50], pe_b2[10], W_nb[25], b_nb[5], w1r0n[5], w2n[5];
#pragma unroll
    for (int j = 0; j < 5; ++j) w_pe1[j] = fw[96 + j];
#pragma unroll
    for (int j = 0; j < 5; ++j) b_pe1[j] = fw[101 + j];
#pragma unroll
    for (int j = 0; j < 50; ++j) pe_w2[j] = fw[106 + j];
#pragma unroll
    for (int j = 0; j < 10; ++j) pe_b2[j] = fw[156 + j];
#pragma unroll
    for (int j = 0; j < 25; ++j) W_nb[j] = fw[166 + j];
#pragma unroll
    for (int j = 0; j < 5; ++j) b_nb[j] = fw[191 + j];
#pragma unroll
    for (int j = 0; j < 5; ++j) w1r0n[j] = fw[196 + j];
#pragma unroll
    for (int j = 0; j < 5; ++j) w2n[j] = fw[201 + j];
    float b2n = fw[206];

    int i = blockIdx.x * 256 + threadIdx.x;
    bool valid = i < N_NODES_C;
    int ii = valid ? i : (N_NODES_C - 1);

    float s = node_acc[ii];
    float t5[5];
#pragma unroll
    for (int k = 0; k < 5; ++k) t5[k] = selu2(fmaf(s, w_pe1[k], b_pe1[k]));
    float he[10];
#pragma unroll
    for (int m = 0; m < 10; ++m) {
        float a = pe_b2[m];
#pragma unroll
        for (int k = 0; k < 5; ++k) a = fmaf(t5[k], pe_w2[k * 10 + m], a);
        he[m] = a;
    }
    float bs[5];
#pragma unroll
    for (int k = 0; k < 5; ++k) {
        float a = b_nb[k];
#pragma unroll
        for (int t = 0; t < 5; ++t) a = fmaf(t5[t], W_nb[t * 5 + k], a);
        bs[k] = a;
    }
    float n = nodes[ii];
#pragma unroll
    for (int it = 0; it < 3; ++it) {
        float a = b2n;
#pragma unroll
        for (int k = 0; k < 5; ++k) {
            float tt = selu2(fmaf(n, w1r0n[k], bs[k]));
            a = fmaf(tt, w2n[k], a);
        }
        n = a;
    }

    int gid = valid ? graph_ids[ii] : -1;
    if (!valid) {
        n = 0.0f;
#pragma unroll
        for (int m = 0; m < 10; ++m) he[m] = 0.0f;
    }

    int gid0 = __shfl(gid, 0, 64);
    bool allsame = __all(gid == gid0) && (gid0 >= 0);
    if (allsame) {
        float v = n;
#pragma unroll
        for (int off = 32; off > 0; off >>= 1) v += __shfl_down(v, off, 64);
        float vh[10];
#pragma unroll
        for (int m = 0; m < 10; ++m) {
            float ww = he[m];
#pragma unroll
            for (int off = 32; off > 0; off >>= 1) ww += __shfl_down(ww, off, 64);
            vh[m] = ww;
        }
        if ((threadIdx.x & 63) == 0) {
            atomAddF(&graph_acc[gid0 * 11 + 0], v);
#pragma unroll
            for (int m = 0; m < 10; ++m) atomAddF(&graph_acc[gid0 * 11 + 1 + m], vh[m]);
        }
    } else if (valid) {
        atomAddF(&graph_acc[gid * 11 + 0], n);
#pragma unroll
        for (int m = 0; m < 10; ++m) atomAddF(&graph_acc[gid * 11 + 1 + m], he[m]);
    }
}

// ---------------- launch ----------------

extern "C" void kernel_launch(void* const* d_in, const int* in_sizes, int n_in,
                              void* d_out, int out_size, void* d_ws, size_t ws_size,
                              hipStream_t stream) {
    const float* nodes     = (const float*)d_in[0];
    const float* edges     = (const float*)d_in[1];
    const int*   senders   = (const int*)d_in[2];
    const int*   receivers = (const int*)d_in[3];
    const int*   graph_ids = (const int*)d_in[4];
    const float* pn_w1 = (const float*)d_in[6];
    const float* pn_b1 = (const float*)d_in[7];
    const float* pn_w2 = (const float*)d_in[8];
    const float* pn_b2 = (const float*)d_in[9];
    const float* ue_w1 = (const float*)d_in[10];
    const float* ue_b1 = (const float*)d_in[11];
    const float* ue_w2 = (const float*)d_in[12];
    const float* ue_b2 = (const float*)d_in[13];
    const float* pe_w1 = (const float*)d_in[14];
    const float* pe_b1 = (const float*)d_in[15];
    const float* pe_w2 = (const float*)d_in[16];
    const float* pe_b2 = (const float*)d_in[17];
    const float* un_w1 = (const float*)d_in[18];
    const float* un_b1 = (const float*)d_in[19];
    const float* un_w2 = (const float*)d_in[20];
    const float* un_b2 = (const float*)d_in[21];
    const float* pr_w1 = (const float*)d_in[22];
    const float* pr_b1 = (const float*)d_in[23];
    const float* pr_w2 = (const float*)d_in[24];
    const float* pr_b2 = (const float*)d_in[25];

    float* ws        = (float*)d_ws;
    float* graph_acc = ws + GRAPH_ACC_OFF;
    float* partials  = ws + PARTIALS_OFF;
    float* fw        = ws + FW_OFF;
    float* outp      = (float*)d_out;

    if (ws_size >= (size_t)WS_WORDS_NEEDED * 4) {
        int* starts_T        = (int*)ws + STARTS_OFF;
        unsigned int* pairs  = (unsigned int*)ws + PAIRS_OFF;

        hipLaunchKernelGGL(k_init, dim3((ZERO_HEAD + 255) / 256), dim3(256), 0, stream, ws,
                           pn_w1, pn_b1, pn_w2, pn_b2, ue_w1, ue_b1, ue_w2, ue_b2,
                           pe_w1, pe_b1, pe_w2, pe_b2, un_w1, un_b1, un_w2, un_b2);
        hipLaunchKernelGGL(k_part, dim3(NPB), dim3(256), 0, stream,
                           nodes, edges, senders, receivers, fw, starts_T, pairs);
        hipLaunchKernelGGL(k_gather, dim3(NBKT), dim3(1024), 0, stream,
                           nodes, graph_ids, fw, starts_T, pairs, graph_acc, partials);
        hipLaunchKernelGGL(k_final, dim3((N_GRAPHS_C + 255) / 256), dim3(256), 0, stream,
                           graph_acc, partials, pr_w1, pr_b1, pr_w2, pr_b2, outp);
    } else {
        float* node_acc = ws + OLD_NODE_ACC_OFF;
        int len4 = OLD_ZERO_WORDS / 4;
        hipLaunchKernelGGL(k_zero, dim3((len4 + 255) / 256), dim3(256), 0, stream, ws, len4);
        hipLaunchKernelGGL(k_fuse, dim3(1), dim3(64), 0, stream,
                           pn_w1, pn_b1, pn_w2, pn_b2, ue_w1, ue_b1, ue_w2, ue_b2,
                           pe_w1, pe_b1, pe_w2, pe_b2, un_w1, un_b1, un_w2, un_b2, fw);
        hipLaunchKernelGGL(k_edges, dim3((NGROUPS_C + 255) / 256), dim3(256), 0, stream,
                           nodes, edges, senders, receivers, fw, node_acc);
        hipLaunchKernelGGL(k_nodes, dim3((N_NODES_C + 255) / 256), dim3(256), 0, stream,
                           nodes, graph_ids, fw, node_acc, graph_acc);
        hipLaunchKernelGGL(k_final, dim3((N_GRAPHS_C + 255) / 256), dim3(256), 0, stream,
                           graph_acc, partials, pr_w1, pr_b1, pr_w2, pr_b2, outp);
    }
}